// Round 5
// baseline (419.212 us; speedup 1.0000x reference)
//
#include <hip/hip_runtime.h>
#include <hip/hip_bf16.h>
#include <cstdint>

// Problem constants (from setup_inputs): B=8192, F=128, L=8192, return_ph=1
#define B_ROWS 8192
#define F_FILT 128
#define L_LEN  8192
#define SPLITK 8
#define KCHUNK (L_LEN / SPLITK)     // 1024 k-values per chunk = 32 gsteps
#define NPH    16                   // LDS phases per block
#define PH_G   2                    // gsteps per phase (64 k)
#define BM     128                  // rows per block (8 waves x 16)
#define MBLK   (B_ROWS / BM)        // 64 -> grid 64 x 8 = 512 blocks (2/CU)

typedef __attribute__((ext_vector_type(4))) float f32x4;
typedef __attribute__((ext_vector_type(8))) short bf16x8;

// fp32 -> bf16 round-to-nearest-even (inputs positive finite; no NaN path)
__device__ __forceinline__ short f2bf(float f) {
  union { float f; unsigned u; } v; v.f = f;
  unsigned u = v.u + 0x7FFFu + ((v.u >> 16) & 1u);
  return (short)(u >> 16);
}

// Packed RNE f32->bf16 (bit-identical to f2bf for positive finite inputs).
__device__ __forceinline__ bf16x8 cvt8(f32x4 x, f32x4 y) {
  union { unsigned u[4]; bf16x8 v; } r;
  asm("v_cvt_pk_bf16_f32 %0, %1, %2" : "=v"(r.u[0]) : "v"(x[0]), "v"(x[1]));
  asm("v_cvt_pk_bf16_f32 %0, %1, %2" : "=v"(r.u[1]) : "v"(x[2]), "v"(x[3]));
  asm("v_cvt_pk_bf16_f32 %0, %1, %2" : "=v"(r.u[2]) : "v"(y[0]), "v"(y[1]));
  asm("v_cvt_pk_bf16_f32 %0, %1, %2" : "=v"(r.u[3]) : "v"(y[2]), "v"(y[3]));
  return r.v;
}

// global -> LDS direct DMA, 16 B/lane. Dest is wave-uniform base + lane*16
// (m104/m108); source is per-lane. Size must be a literal (guide §5).
__device__ __forceinline__ void gload16(const void* g, void* l) {
  __builtin_amdgcn_global_load_lds(
      (const __attribute__((address_space(1))) void*)g,
      (__attribute__((address_space(3))) void*)l, 16, 0, 0);
}

// Kernel 1: build Bp = (trans * trapz_w) in MFMA B-operand LANE ORDER:
// slot o = (gstep*8 + j)*64 + lane holds WT[j*16 + (lane&15)][gstep*32 + (lane>>4)*8 .. +7]
__global__ void build_wt(const float* __restrict__ trans,
                         const float* __restrict__ lam,
                         ushort* __restrict__ bp) {
  int o = blockIdx.x * blockDim.x + threadIdx.x;   // over F*L/8 slots
  int lane = o & 63, j = (o >> 6) & 7, gs = o >> 9;
  int f = j * 16 + (lane & 15);
  int k = gs * 32 + (lane >> 4) * 8;
  bf16x8 h;
#pragma unroll
  for (int i = 0; i < 8; ++i) {
    int l = k + i;
    float lo = (l > 0)         ? lam[l - 1] : lam[0];
    float hi = (l < L_LEN - 1) ? lam[l + 1] : lam[L_LEN - 1];
    h[i] = f2bf(trans[(size_t)f * L_LEN + l] * (0.5f * (hi - lo)));  // trapz weight
  }
  *(bf16x8*)(bp + (size_t)o * 8) = h;
}

// Kernel 2: split-K GEMM, BOTH operands staged via global_load_lds.
// R4 diagnosis: gemm pinned at ~147 us across 8/16/32 waves/CU and B-in-LDS
// variants -> not wave-bound, not B-bound. Culprit: direct-from-global MFMA
// A-fragments (16 B/lane, 32 KB row stride) touch 16+ distinct cache lines
// per instruction -> per-CU miss-tracking (MSHR) caps A fill at ~11 GB/s/CU
// ~= 95-100 us for 268 MB, immune to occupancy. Fix: stage A contiguously
// (each gld_lds covers 4 x 256 B row segments = 8 cache lines) into a linear
// [128][64] fp32 LDS tile; the per-lane fragment scatter moves to LDS reads,
// where the 32 B/lane pattern hits all 32 banks uniformly (no swizzle needed).
__global__ __launch_bounds__(512, 4)
void gemm_splitk(const float* __restrict__ A,
                 const ushort* __restrict__ BP,
                 float* __restrict__ P /* [SPLITK][B_ROWS][F_FILT] */) {
  __shared__ float  Alds[BM * 64];              // 32 KB: A tile [128 rows][64 k]
  __shared__ ushort Blds[PH_G * 8 * 64 * 8];    // 16 KB: 2 gsteps of lane-ordered B

  const int tid  = threadIdx.x;
  const int lane = tid & 63;
  const int wave = tid >> 6;
  const int rl = lane & 15;        // A row within 16-row tile / C col
  const int kg = lane >> 4;        // k-quad 0..3
  const int mb = blockIdx.x * BM;
  const int s  = blockIdx.y;

  f32x4 acc[8] = {};               // 32 VGPRs

  // A staging: 4 chunks/wave; chunk c = LDS bytes [(wave*4+c)*1024, +1KB).
  // Lane's LDS byte p = chunk_base + lane*16 -> row = p>>8, float col = (p&255)>>2.
  const int ap0 = wave * 4096 + lane * 16;

  for (int ph = 0; ph < NPH; ++ph) {
    const int ks = s * KCHUNK + ph * (PH_G * 32);   // k start of this phase
    const int G0 = s * (KCHUNK / 32) + ph * PH_G;   // global gstep index
    // ---- stage A: 32 KB, fully linear LDS, contiguous-segment sources ----
#pragma unroll
    for (int c = 0; c < 4; ++c) {
      const int p = ap0 + c * 1024;
      const int arow = p >> 8;                      // 0..127
      const int acol = (p & 255) >> 2;              // 0..63
      gload16(A + (size_t)(mb + arow) * L_LEN + ks + acol,
              (char*)Alds + (wave * 4 + c) * 1024);
    }
    // ---- stage B: 16 KB flat copy of BP phase chunk (already lane-ordered) ----
#pragma unroll
    for (int c = 0; c < 2; ++c) {
      const int pb = (wave * 2 + c) * 1024 + lane * 16;
      gload16((const char*)(BP + (size_t)G0 * 4096) + pb,
              (char*)Blds + (wave * 2 + c) * 1024);
    }
    __syncthreads();   // compiler drains vmcnt before s_barrier -> stage visible
    // ---- compute 2 gsteps from LDS ----
#pragma unroll
    for (int g = 0; g < PH_G; ++g) {
      const int row = wave * 16 + rl;
      const char* ab = (const char*)Alds + row * 256 + g * 128 + kg * 32;
      f32x4 ac0 = *(const f32x4*)(ab);
      f32x4 ac1 = *(const f32x4*)(ab + 16);
      bf16x8 af = cvt8(ac0, ac1);
      const ushort* bb = Blds + g * 4096 + lane * 8;
#pragma unroll
      for (int j = 0; j < 8; ++j) {
        bf16x8 b = *(const bf16x8*)(bb + j * 512);  // ds_read_b128, conflict-free
        acc[j] = __builtin_amdgcn_mfma_f32_16x16x32_bf16(af, b, acc[j], 0, 0, 0);
      }
    }
    __syncthreads();   // all reads done before next phase's stage overwrites
  }

  // epilogue: C/D layout col(N)=lane&15, row(M)=kg*4+reg  [verified m89/m91]
  const int m0 = mb + wave * 16;
  float* po = P + ((size_t)s * B_ROWS + m0) * F_FILT;
#pragma unroll
  for (int r = 0; r < 4; ++r) {
    const int row = kg * 4 + r;
#pragma unroll
    for (int j = 0; j < 8; ++j)
      po[(size_t)row * F_FILT + j * 16 + rl] = acc[j][r];
  }
}

// Kernel 3: sum split-K partials + -2.5*log10, vectorized x4
__global__ void finish(const float* __restrict__ P, float* __restrict__ out) {
  int t = blockIdx.x * blockDim.x + threadIdx.x;  // over B*F/4
  f32x4 s = {};
#pragma unroll
  for (int i = 0; i < SPLITK; ++i) {
    f32x4 p = *(const f32x4*)(P + (size_t)i * ((size_t)B_ROWS * F_FILT) + (size_t)t * 4);
    s[0] += p[0]; s[1] += p[1]; s[2] += p[2]; s[3] += p[3];
  }
  f32x4 o;
  o[0] = -2.5f * log10f(s[0]);
  o[1] = -2.5f * log10f(s[1]);
  o[2] = -2.5f * log10f(s[2]);
  o[3] = -2.5f * log10f(s[3]);
  *(f32x4*)(out + (size_t)t * 4) = o;
}

extern "C" void kernel_launch(void* const* d_in, const int* in_sizes, int n_in,
                              void* d_out, int out_size, void* d_ws, size_t ws_size,
                              hipStream_t stream) {
  const float* A    = (const float*)d_in[0];   // l_target [B, L] fp32
  const float* T    = (const float*)d_in[1];   // trans_filter [F, L] fp32
  const float* lam  = (const float*)d_in[2];   // lam [L] fp32
  // d_in[3] = return_ph (1 per setup_inputs; only that path implemented)

  ushort* bp = (ushort*)d_ws;                                  // 2 MB lane-ordered bf16 WT
  float*  P  = (float*)((char*)d_ws + (size_t)F_FILT * L_LEN * sizeof(ushort)); // 32 MB partials
  float*  out = (float*)d_out;

  build_wt<<<(F_FILT * L_LEN / 8) / 256, 256, 0, stream>>>(T, lam, bp);
  gemm_splitk<<<dim3(MBLK, SPLITK), 512, 0, stream>>>(A, bp, P);
  finish<<<(B_ROWS * F_FILT / 4) / 256, 256, 0, stream>>>(P, out);
}